// Round 14
// baseline (390.801 us; speedup 1.0000x reference)
//
#include <hip/hip_runtime.h>
#include <hip/hip_bf16.h>
#include <stdint.h>

#define BB 256
#define TT 128
#define SS 16
#define QQ 16
#define EE 128
#define KK 20
#define VOCAB 50020
#define KB_ROWS 10   // k-rows per scan block (2 blocks per batch)
#define XK_STR 24    // padded xk row stride (halves at 0 and 12, 16B-aligned)

typedef __attribute__((ext_vector_type(8))) _Float16 h8v;         // 8 fp16 (4 VGPR)
typedef __attribute__((ext_vector_type(2))) __fp16 fp2v;          // builtin's return type
typedef __attribute__((ext_vector_type(4))) unsigned short u4h;   // 4 x u16 (b64)
typedef __attribute__((ext_vector_type(4))) float f4v;            // MFMA acc
#define MFMA16(a,b,c) __builtin_amdgcn_mfma_f32_16x16x32_f16(a,b,c,0,0,0)

static __device__ __forceinline__ unsigned pk2u(fp2v h){
  union { fp2v h; unsigned u; } c; c.h = h; return c.u;
}
static __device__ __forceinline__ float pk_lo(fp2v h){ return (float)h[0]; }
static __device__ __forceinline__ float pk_hi(fp2v h){ return (float)h[1]; }
static __device__ __forceinline__ unsigned short h1u(_Float16 h){
  union { _Float16 h; unsigned short u; } c; c.h = h; return c.u;
}
// fp16 2-term split of 8 f32 (RN, used outside the hot loop)
static __device__ __forceinline__ void split2_8(const float* v, h8v& h, h8v& l){
  #pragma unroll
  for (int j=0;j<8;++j){
    _Float16 hb = (_Float16)v[j];
    float hf = (float)hb;
    h[j] = hb;
    l[j] = (_Float16)(v[j]-hf);
  }
}
// 16-lane row sum via DPP (quad_perm xor1, xor2, row_ror:4, row_ror:8)
static __device__ __forceinline__ float dpp_add16(float x){
  int v;
  v = __builtin_amdgcn_update_dpp(0, __float_as_int(x), 0xB1, 0xF, 0xF, true);
  x += __int_as_float(v);
  v = __builtin_amdgcn_update_dpp(0, __float_as_int(x), 0x4E, 0xF, 0xF, true);
  x += __int_as_float(v);
  v = __builtin_amdgcn_update_dpp(0, __float_as_int(x), 0x124, 0xF, 0xF, true);
  x += __int_as_float(v);
  v = __builtin_amdgcn_update_dpp(0, __float_as_int(x), 0x128, 0xF, 0xF, true);
  x += __int_as_float(v);
  return x;
}
// hardware transpose read: quarter-wave reads 128B region, lane gets column (l&15)
template<int IMM>
static __device__ __forceinline__ u4h tr_read(unsigned va){
  u4h d;
  asm volatile("ds_read_b64_tr_b16 %0, %1 offset:%c2" : "=v"(d) : "v"(va), "i"(IMM));
  return d;
}
static __device__ __forceinline__ h8v cat8h(u4h a, u4h b){
  union { u4h p[2]; h8v v; } u; u.p[0]=a; u.p[1]=b; return u.v;
}
// A-frag (state) for plane P (0=hi,1=lo), k-slice K4 within current ping buffer
#define LDA(P,K4) cat8h(tr_read<(P)*4096+(K4)*1024>(va), tr_read<(P)*4096+(K4)*1024+128>(va))

// ---------------- workspace layout (floats) ----------------
static const size_t OFF_SENC = 0;                              // B*T*E
static const size_t OFF_QENC = OFF_SENC + (size_t)BB*TT*EE;    // B*E
static const size_t OFF_CKF  = OFF_QENC + (size_t)BB*EE;       // K*E
static const size_t OFF_XW   = OFF_CKF  + (size_t)KK*EE;       // B*T*E
static const size_t OFF_Z    = OFF_XW   + (size_t)BB*TT*EE;    // B*E
static const size_t OFF_XK   = OFF_Z    + (size_t)BB*EE;       // B*T*XK_STR
static const size_t OFF_ST   = OFF_XK   + (size_t)BB*TT*XK_STR; // B*K*E

// ---------------- kernel 1: fused query-embed + Ckf ----------------
// blocks [0, BB/8): query bag-sum.  blocks [BB/8, BB/8+KK): Ckf rows.
__global__ __launch_bounds__(256) void k_small(
    const int* __restrict__ query, const float* __restrict__ emb,
    const float* __restrict__ qmask, const float* __restrict__ V,
    const float* __restrict__ bias, float* __restrict__ qenc,
    float* __restrict__ Ckf)
{
  int tid = threadIdx.x;
  int bid = blockIdx.x;
  if (bid < BB/8){
    int row = bid*8 + (tid>>5);
    int e4 = (tid&31)*4;
    float4 acc = make_float4(0.f,0.f,0.f,0.f);
    #pragma unroll
    for (int s=0; s<QQ; ++s) {
      int id = query[row*QQ + s];
      float4 ev = *(const float4*)(emb + (size_t)id*EE + e4);
      float4 mv = *(const float4*)(qmask + s*EE + e4);
      acc.x += ev.x*mv.x; acc.y += ev.y*mv.y; acc.z += ev.z*mv.z; acc.w += ev.w*mv.w;
    }
    *(float4*)(qenc + (size_t)row*EE + e4) = acc;
  } else {
    int k = bid - BB/8;
    if (tid < 128){
      int f = tid;
      const float* key = emb + (size_t)(VOCAB-KK+k)*EE;
      const float* vr  = V + (size_t)f*EE;
      float acc = bias[f];
      for (int e=0; e<EE; e+=4) {
        float4 kv = *(const float4*)(key + e);
        float4 vv = *(const float4*)(vr + e);
        acc += kv.x*vv.x + kv.y*vv.y + kv.z*vv.z + kv.w*vv.w;
      }
      Ckf[k*EE + f] = acc;
    }
  }
}

// ---------------- kernel 2: fused story-embed + xw + xk ----------------
// 64 rows per block: gather-embed into LDS, write s_enc, then GEMM xw, xk.
__global__ __launch_bounds__(256) void k_enc_xw(
    const int* __restrict__ tok, const float* __restrict__ emb,
    const float* __restrict__ smask, const float* __restrict__ W,
    float* __restrict__ senc, float* __restrict__ xw,
    float* __restrict__ xk)
{
  __shared__ float xs[64*EE];        // 32 KB
  __shared__ float keys_s[KK*EE];    // 10 KB
  int tid = threadIdx.x;
  int r0 = blockIdx.x*64;
  // gather-embed 64 rows directly into LDS + global s_enc
  for (int i=0;i<8;++i){
    int row = i*8 + (tid>>5);
    int e4 = (tid&31)*4;
    float4 acc = make_float4(0.f,0.f,0.f,0.f);
    #pragma unroll
    for (int s=0; s<SS; ++s) {
      int id = tok[(size_t)(r0+row)*SS + s];
      float4 ev = *(const float4*)(emb + (size_t)id*EE + e4);
      float4 mv = *(const float4*)(smask + s*EE + e4);
      acc.x += ev.x*mv.x; acc.y += ev.y*mv.y; acc.z += ev.z*mv.z; acc.w += ev.w*mv.w;
    }
    *(float4*)(xs + row*EE + e4) = acc;
    *(float4*)(senc + (size_t)(r0+row)*EE + e4) = acc;
  }
  for (int idx=tid; idx<KK*EE; idx+=256)
    keys_s[idx] = emb[(size_t)(VOCAB-KK + (idx>>7))*EE + (idx&127)];
  __syncthreads();
  int f  = tid & 127;
  int rh = tid >> 7;
  float acc[32];
  #pragma unroll
  for (int i=0;i<32;++i) acc[i]=0.f;
  const float* wr = W + (size_t)f*EE;
  for (int e4=0; e4<EE; e4+=4) {
    float4 w4 = *(const float4*)(wr + e4);
    #pragma unroll
    for (int rr=0; rr<32; ++rr) {
      float4 x4 = *(const float4*)(xs + (rh*32+rr)*EE + e4);
      acc[rr] += w4.x*x4.x + w4.y*x4.y + w4.z*x4.z + w4.w*x4.w;
    }
  }
  #pragma unroll
  for (int rr=0; rr<32; ++rr)
    xw[(size_t)(r0 + rh*32 + rr)*EE + f] = acc[rr];
  for (int i=0;i<5;++i){
    int task = tid + i*256;
    int r = task/KK, k = task - r*KK;
    float a = 0.f;
    for (int e=0; e<EE; e+=4){
      float4 x4 = *(const float4*)(xs + r*EE + e);
      float4 k4 = *(const float4*)(keys_s + k*EE + e);
      a += x4.x*k4.x + x4.y*k4.y + x4.z*k4.z + x4.w*k4.w;
    }
    int ki = k < 10 ? k : k + 2;   // halves at 0 and 12
    xk[(size_t)(r0+r)*XK_STR + ki] = a;
  }
}

// ---------------- kernel 4: MFMA scan — frozen R13 structure (validated 242 us) ----
struct ScanLds {
  unsigned short st[2][2][EE][16];  // 16384 B (buf, plane hi/lo, e, k-row)
  unsigned short xp[2][2][EE];      // 1024 B
  float npart[2][4][16];            // 512 B
};

__global__ __launch_bounds__(256) void k_scan(
    const float* __restrict__ emb, const float* __restrict__ U,
    const float* __restrict__ senc, const float* __restrict__ xw,
    const float* __restrict__ xk, const float* __restrict__ Ckf,
    const float* __restrict__ prelu_a, float* __restrict__ zst)
{
  __shared__ ScanLds L;
  int tid = threadIdx.x;
  int bid = blockIdx.x;
  int b   = bid >> 1, kb = bid & 1;
  int l   = tid & 63, cg = tid >> 6;
  int q   = l >> 4,  c  = l & 15;
  int col[2] = { cg*32 + c, cg*32 + 16 + c };

  // ---- zero both state buffers (pad rows must stay 0) ----
  for (int idx = tid; idx < 2*2*EE*16; idx += 256) ((unsigned short*)L.st)[idx] = 0;
  __syncthreads();
  // ---- init s_hat_0 = keys (raw, unnormalized — matches reference state0) ----
  for (int idx = tid; idx < KB_ROWS*EE; idx += 256){
    int row = idx >> 7, e = idx & 127;
    float v = emb[(size_t)(VOCAB - KK + kb*KB_ROWS + row)*EE + e];
    _Float16 hb = (_Float16)v;
    _Float16 lb = (_Float16)(v - (float)hb);
    L.st[0][0][e][row] = h1u(hb);
    L.st[0][1][e][row] = h1u(lb);
  }
  // ---- B-frags: U columns, fp16 hi/lo, constant across scan ----
  h8v bh[2][4], bl[2][4];
  #pragma unroll
  for (int nt=0;nt<2;++nt)
    #pragma unroll
    for (int kk=0;kk<4;++kk){
      float tmp[8];
      const float* up = U + (size_t)col[nt]*EE + kk*32 + q*8;
      *(float4*)&tmp[0] = *(const float4*)up;
      *(float4*)&tmp[4] = *(const float4*)(up+4);
      split2_8(tmp, bh[nt][kk], bl[nt][kk]);
    }
  // ---- per-lane constants; nsv = register copy of own s_hat values ----
  float Creg[2][4], pa2[2], nsv[2][4];
  bool realr[4];
  #pragma unroll
  for (int r=0;r<4;++r) realr[r] = (4*q + r) < KB_ROWS;
  #pragma unroll
  for (int nt=0;nt<2;++nt){
    pa2[nt] = prelu_a[col[nt]];
    #pragma unroll
    for (int r=0;r<4;++r){
      int lr = 4*q + r;
      Creg[nt][r] = realr[r] ? Ckf[(kb*KB_ROWS+lr)*EE + col[nt]] : 0.f;
      nsv[nt][r]  = realr[r] ? emb[(size_t)(VOCAB-KK+kb*KB_ROWS+lr)*EE + col[nt]] : 0.f;
    }
  }

  const float* xrow  = senc + (size_t)b*TT*EE;
  const float* xwrow = xw   + (size_t)b*TT*EE;
  const float* xkrow = xk   + (size_t)b*TT*XK_STR + kb*12;   // 16B-aligned half

  // t=0 staging into buf 0
  if (tid < EE){
    float v = xrow[tid];
    _Float16 hb = (_Float16)v;
    _Float16 lb = (_Float16)(v - (float)hb);
    L.xp[0][0][tid] = h1u(hb); L.xp[0][1][tid] = h1u(lb);
  }
  float xwc[2] = { xwrow[col[0]], xwrow[col[1]] };
  float xkc[4];
  {
    f4v xk4 = {0.f,0.f,0.f,0.f};
    if (q < 3) xk4 = *(const f4v*)(xkrow + 4*q);
    #pragma unroll
    for (int r=0;r<4;++r) xkc[r] = realr[r] ? xk4[r] : 0.f;
  }

  unsigned va0 = (unsigned)(uintptr_t)&L.st[0][0][0][0] + q*256 + c*8;
  __syncthreads();

  for (int t=0; t<TT; ++t){
    int p = t & 1, pn = p ^ 1;
    unsigned va = va0 + p*8192;
    const unsigned short (*xpp)[EE] = L.xp[p];

    // ---- inv norms of s_hat_t (from prev step's npart); t=0: state0 unnormalized ----
    float invr[4];
    if (t > 0){
      f4v p0 = *(const f4v*)&L.npart[p][0][4*q];
      f4v p1 = *(const f4v*)&L.npart[p][1][4*q];
      f4v p2 = *(const f4v*)&L.npart[p][2][4*q];
      f4v p3 = *(const f4v*)&L.npart[p][3][4*q];
      f4v ss = p0 + p1 + p2 + p3;
      #pragma unroll
      for (int r=0;r<4;++r)
        invr[r] = __builtin_amdgcn_rcpf(__builtin_amdgcn_sqrtf(ss[r]) + 1e-8f);
    } else {
      #pragma unroll
      for (int r=0;r<4;++r) invr[r] = 1.0f;
    }

    // ---- prefetch t+1 globals ----
    float nxv = 0.f, xwn[2] = {0.f,0.f};
    f4v xk4n = {0.f,0.f,0.f,0.f};
    if (t+1 < TT){
      if (tid < EE) nxv = xrow[(size_t)(t+1)*EE + tid];
      xwn[0] = xwrow[(size_t)(t+1)*EE + col[0]];
      xwn[1] = xwrow[(size_t)(t+1)*EE + col[1]];
      if (q < 3) xk4n = *(const f4v*)(xkrow + (size_t)(t+1)*XK_STR + 4*q);
    }

    // ---- A-frags (s_hat_t) via hardware transpose reads: hi + lo planes ----
    h8v Ah[4] = { LDA(0,0), LDA(0,1), LDA(0,2), LDA(0,3) };
    h8v Al[4] = { LDA(1,0), LDA(1,1), LDA(1,2), LDA(1,3) };
    asm volatile("s_waitcnt lgkmcnt(0)" ::: "memory");
    __builtin_amdgcn_sched_barrier(0);

    f4v z4 = {0.f,0.f,0.f,0.f};
    f4v acc[2][2] = {{z4,z4},{z4,z4}};
    f4v gac[2] = {z4,z4};
    #pragma unroll
    for (int kk=0; kk<4; ++kk){
      int h = kk>>1;
      h8v xh = *(const h8v*)&xpp[0][kk*32 + q*8];
      h8v xl = *(const h8v*)&xpp[1][kk*32 + q*8];
      #pragma unroll
      for (int nt=0;nt<2;++nt){
        acc[nt][h] = MFMA16(Al[kk], bh[nt][kk], acc[nt][h]);
        acc[nt][h] = MFMA16(Ah[kk], bl[nt][kk], acc[nt][h]);
        acc[nt][h] = MFMA16(Ah[kk], bh[nt][kk], acc[nt][h]);
      }
      gac[h] = MFMA16(Al[kk], xh, gac[h]);
      gac[h] = MFMA16(Ah[kk], xl, gac[h]);
      gac[h] = MFMA16(Ah[kk], xh, gac[h]);
    }
    f4v acc0 = acc[0][0] + acc[0][1];
    f4v acc1 = acc[1][0] + acc[1][1];
    f4v gacc = gac[0] + gac[1];

    // ---- deferred normalization: scale GEMM rows by inv; gate; new state ----
    float s2[4];
    #pragma unroll
    for (int r=0;r<4;++r){
      float graw = gacc[r]*invr[r] + xkc[r];
      float g = __builtin_amdgcn_rcpf(1.0f + __builtin_amdgcn_exp2f(-1.442695040889f * graw));
      float s2r = 0.f;
      #pragma unroll
      for (int nt=0;nt<2;++nt){
        float so = nsv[nt][r] * invr[r];                       // normalized old state
        float cv = (nt ? acc1[r] : acc0[r])*invr[r] + Creg[nt][r] + xwc[nt];
        cv = cv > 0.f ? cv : pa2[nt]*cv;
        float n = so + g*cv;
        nsv[nt][r] = realr[r] ? (n > 0.f ? n : 1.0f) : 0.f;    // s_hat_{t+1}
        s2r += n*n;
      }
      s2[r] = dpp_add16(s2r);                                  // 16-lane DPP reduce
    }
    if (c == 0){
      f4v np; np[0]=s2[0]; np[1]=s2[1]; np[2]=s2[2]; np[3]=s2[3];
      *(f4v*)&L.npart[pn][cg][4*q] = np;
    }

    // ---- store s_hat_{t+1} (pkrtz split, uint2 stores) + stage x_{t+1} ----
    #pragma unroll
    for (int nt=0;nt<2;++nt){
      float v0=nsv[nt][0], v1=nsv[nt][1], v2=nsv[nt][2], v3=nsv[nt][3];
      fp2v pa = __builtin_amdgcn_cvt_pkrtz(v0, v1);
      fp2v pb = __builtin_amdgcn_cvt_pkrtz(v2, v3);
      float r0 = v0 - pk_lo(pa);
      float r1 = v1 - pk_hi(pa);
      float r2 = v2 - pk_lo(pb);
      float r3 = v3 - pk_hi(pb);
      fp2v pc = __builtin_amdgcn_cvt_pkrtz(r0, r1);
      fp2v pd = __builtin_amdgcn_cvt_pkrtz(r2, r3);
      *(uint2*)&L.st[pn][0][col[nt]][4*q] = make_uint2(pk2u(pa), pk2u(pb));
      *(uint2*)&L.st[pn][1][col[nt]][4*q] = make_uint2(pk2u(pc), pk2u(pd));
    }
    if (t+1 < TT && tid < EE){
      _Float16 hb = (_Float16)nxv;
      _Float16 lb = (_Float16)(nxv - (float)hb);
      L.xp[pn][0][tid] = h1u(hb); L.xp[pn][1][tid] = h1u(lb);
    }
    xwc[0]=xwn[0]; xwc[1]=xwn[1];
    #pragma unroll
    for (int r=0;r<4;++r) xkc[r] = realr[r] ? xk4n[r] : 0.f;
    __syncthreads();                              // ONE barrier per step
  }

  // ---- finalize: normalize last s_hat from registers + final npart ----
  {
    int pf = TT & 1;   // buffer holding final npart
    f4v p0 = *(const f4v*)&L.npart[pf][0][4*q];
    f4v p1 = *(const f4v*)&L.npart[pf][1][4*q];
    f4v p2 = *(const f4v*)&L.npart[pf][2][4*q];
    f4v p3 = *(const f4v*)&L.npart[pf][3][4*q];
    f4v ss = p0 + p1 + p2 + p3;
    #pragma unroll
    for (int r=0;r<4;++r){
      if (realr[r]){
        float inv = __builtin_amdgcn_rcpf(__builtin_amdgcn_sqrtf(ss[r]) + 1e-8f);
        #pragma unroll
        for (int nt=0;nt<2;++nt)
          zst[((size_t)b*KK + kb*KB_ROWS + 4*q + r)*EE + col[nt]] = nsv[nt][r]*inv;
      }
    }
  }
}

// ---------------- kernel 4b: tail (attention + u + z), needs all 20 k ----------------
__global__ __launch_bounds__(128) void k_tail(
    const float* __restrict__ zst, const float* __restrict__ qenc,
    const float* __restrict__ prelu_a, const float* __restrict__ H,
    float* __restrict__ zout)
{
  __shared__ float st[KK*EE];
  __shared__ float us[EE];
  __shared__ float red[2][KK];
  __shared__ float gs[KK];
  int b = blockIdx.x, tid = threadIdx.x;
  for (int i = tid; i < KK*EE; i += 128) st[i] = zst[(size_t)b*KK*EE + i];
  float qv = qenc[(size_t)b*EE + tid];
  __syncthreads();
  int wv = tid >> 6, ln = tid & 63;
  for (int k=0;k<KK;++k){
    float p = qv * st[k*EE + tid];
    #pragma unroll
    for (int off=32; off; off>>=1) p += __shfl_xor(p, off);
    if (ln == 0) red[wv][k] = p;
  }
  __syncthreads();
  if (tid == 0){
    float mx = -1e30f, gg[KK];
    for (int k=0;k<KK;++k){ float v = red[0][k]+red[1][k]; gg[k]=v; mx = fmaxf(mx, v); }
    float s = 0.f;
    for (int k=0;k<KK;++k){ float e_ = expf(gg[k]-mx); gg[k]=e_; s += e_; }
    for (int k=0;k<KK;++k) gs[k] = gg[k]/s;
  }
  __syncthreads();
  float u_ = 0.f;
  #pragma unroll
  for (int k=0;k<KK;++k) u_ += gs[k]*st[k*EE + tid];
  us[tid] = u_;
  __syncthreads();
  float hp = 0.f;
  const float* hr = H + (size_t)tid*EE;
  for (int e=0; e<EE; e+=4){
    float4 h4 = *(const float4*)(hr + e);
    float4 u4 = *(const float4*)(us + e);
    hp += h4.x*u4.x + h4.y*u4.y + h4.z*u4.z + h4.w*u4.w;
  }
  float zv = qv + hp;
  float pat = prelu_a[tid];
  zv = zv > 0.f ? zv : pat*zv;
  zout[(size_t)b*EE + tid] = zv;
}

// ---------------- kernel 5: y = z @ R^T via fp16-split MFMA, 4 M-tiles/block ----
// Wave: 64 b-rows x 64 v-cols. B-frags (R) loaded once, reused across 4 M-tiles.
__global__ __launch_bounds__(256) void k_out(
    const float* __restrict__ z, const float* __restrict__ R,
    float* __restrict__ y)
{
  int tid = threadIdx.x;
  int w = tid >> 6, l = tid & 63;
  int q = l >> 4, cc = l & 15;
  int b0 = blockIdx.y * 64;
  int vbase = blockIdx.x * 256 + w * 64;

  // A-frags: z rows for 4 M-tiles (row = lane&15 within tile)
  h8v ah[4][4], al[4][4];
  #pragma unroll
  for (int mt=0;mt<4;++mt){
    const float* zr = z + (size_t)(b0 + mt*16 + cc)*EE;
    #pragma unroll
    for (int kk=0;kk<4;++kk){
      float tmp[8];
      *(float4*)&tmp[0] = *(const float4*)(zr + kk*32 + q*8);
      *(float4*)&tmp[4] = *(const float4*)(zr + kk*32 + q*8 + 4);
      split2_8(tmp, ah[mt][kk], al[mt][kk]);
    }
  }
  #pragma unroll
  for (int vt=0; vt<4; ++vt){
    int v = vbase + vt*16 + cc;
    int vc = v < VOCAB ? v : VOCAB-1;
    const float* rr = R + (size_t)vc*EE;
    h8v bh[4], bl[4];
    #pragma unroll
    for (int kk=0;kk<4;++kk){
      float tmp[8];
      *(float4*)&tmp[0] = *(const float4*)(rr + kk*32 + q*8);
      *(float4*)&tmp[4] = *(const float4*)(rr + kk*32 + q*8 + 4);
      split2_8(tmp, bh[kk], bl[kk]);
    }
    f4v acc0 = {0.f,0.f,0.f,0.f};
    f4v acc1 = {0.f,0.f,0.f,0.f};
    f4v acc2 = {0.f,0.f,0.f,0.f};
    f4v acc3 = {0.f,0.f,0.f,0.f};
    #pragma unroll
    for (int kk=0;kk<4;++kk){
      acc0 = MFMA16(al[0][kk], bh[kk], acc0);
      acc0 = MFMA16(ah[0][kk], bl[kk], acc0);
      acc0 = MFMA16(ah[0][kk], bh[kk], acc0);
      acc1 = MFMA16(al[1][kk], bh[kk], acc1);
      acc1 = MFMA16(ah[1][kk], bl[kk], acc1);
      acc1 = MFMA16(ah[1][kk], bh[kk], acc1);
      acc2 = MFMA16(al[2][kk], bh[kk], acc2);
      acc2 = MFMA16(ah[2][kk], bl[kk], acc2);
      acc2 = MFMA16(ah[2][kk], bh[kk], acc2);
      acc3 = MFMA16(al[3][kk], bh[kk], acc3);
      acc3 = MFMA16(ah[3][kk], bl[kk], acc3);
      acc3 = MFMA16(ah[3][kk], bh[kk], acc3);
    }
    if (v < VOCAB){
      #pragma unroll
      for (int r=0;r<4;++r){
        y[(size_t)(b0 +      q*4 + r)*VOCAB + v] = acc0[r];
        y[(size_t)(b0 + 16 + q*4 + r)*VOCAB + v] = acc1[r];
        y[(size_t)(b0 + 32 + q*4 + r)*VOCAB + v] = acc2[r];
        y[(size_t)(b0 + 48 + q*4 + r)*VOCAB + v] = acc3[r];
      }
    }
  }
}

// ---------------- launch ----------------
extern "C" void kernel_launch(void* const* d_in, const int* in_sizes, int n_in,
                              void* d_out, int out_size, void* d_ws, size_t ws_size,
                              hipStream_t stream)
{
  const int*   story = (const int*)d_in[0];
  const int*   query = (const int*)d_in[1];
  const float* emb   = (const float*)d_in[2];
  const float* smask = (const float*)d_in[3];
  const float* qmask = (const float*)d_in[4];
  const float* pa    = (const float*)d_in[5];
  const float* U     = (const float*)d_in[6];
  const float* V     = (const float*)d_in[7];
  const float* W     = (const float*)d_in[8];
  const float* bias  = (const float*)d_in[9];
  const float* H     = (const float*)d_in[10];
  const float* R     = (const float*)d_in[11];
  float* y  = (float*)d_out;
  float* ws = (float*)d_ws;

  float* s_enc = ws + OFF_SENC;
  float* q_enc = ws + OFF_QENC;
  float* Ckf   = ws + OFF_CKF;
  float* xw    = ws + OFF_XW;
  float* z     = ws + OFF_Z;
  float* xk    = ws + OFF_XK;
  float* zst   = ws + OFF_ST;

  k_small<<<dim3(BB/8 + KK), 256, 0, stream>>>(query, emb, qmask, V, bias, q_enc, Ckf);
  k_enc_xw<<<dim3(BB*TT/64), 256, 0, stream>>>(story, emb, smask, W, s_enc, xw, xk);

  k_scan<<<dim3(BB*2), 256, 0, stream>>>(emb, U, s_enc, xw, xk, Ckf, pa, zst);
  k_tail<<<dim3(BB), 128, 0, stream>>>(zst, q_enc, pa, H, z);

  k_out<<<dim3((VOCAB+255)/256, BB/64), 256, 0, stream>>>(z, R, y);
}

// Round 15
// 372.573 us; speedup vs baseline: 1.0489x; 1.0489x over previous
//
#include <hip/hip_runtime.h>
#include <hip/hip_bf16.h>
#include <stdint.h>

#define BB 256
#define TT 128
#define SS 16
#define QQ 16
#define EE 128
#define KK 20
#define VOCAB 50020
#define KB_ROWS 10   // k-rows per scan block (2 blocks per batch)
#define XK_STR 24    // padded xk row stride (halves at 0 and 12, 16B-aligned)

typedef __attribute__((ext_vector_type(8))) _Float16 h8v;         // 8 fp16 (4 VGPR)
typedef __attribute__((ext_vector_type(2))) __fp16 fp2v;          // builtin's return type
typedef __attribute__((ext_vector_type(4))) unsigned short u4h;   // 4 x u16 (b64)
typedef __attribute__((ext_vector_type(4))) float f4v;            // MFMA acc
#define MFMA16(a,b,c) __builtin_amdgcn_mfma_f32_16x16x32_f16(a,b,c,0,0,0)

static __device__ __forceinline__ unsigned pk2u(fp2v h){
  union { fp2v h; unsigned u; } c; c.h = h; return c.u;
}
static __device__ __forceinline__ float pk_lo(fp2v h){ return (float)h[0]; }
static __device__ __forceinline__ float pk_hi(fp2v h){ return (float)h[1]; }
static __device__ __forceinline__ unsigned short h1u(_Float16 h){
  union { _Float16 h; unsigned short u; } c; c.h = h; return c.u;
}
// fp16 2-term split of 8 f32 (RN, used outside the hot loop)
static __device__ __forceinline__ void split2_8(const float* v, h8v& h, h8v& l){
  #pragma unroll
  for (int j=0;j<8;++j){
    _Float16 hb = (_Float16)v[j];
    float hf = (float)hb;
    h[j] = hb;
    l[j] = (_Float16)(v[j]-hf);
  }
}
// 16-lane row sum via DPP (quad_perm xor1, xor2, row_ror:4, row_ror:8)
static __device__ __forceinline__ float dpp_add16(float x){
  int v;
  v = __builtin_amdgcn_update_dpp(0, __float_as_int(x), 0xB1, 0xF, 0xF, true);
  x += __int_as_float(v);
  v = __builtin_amdgcn_update_dpp(0, __float_as_int(x), 0x4E, 0xF, 0xF, true);
  x += __int_as_float(v);
  v = __builtin_amdgcn_update_dpp(0, __float_as_int(x), 0x124, 0xF, 0xF, true);
  x += __int_as_float(v);
  v = __builtin_amdgcn_update_dpp(0, __float_as_int(x), 0x128, 0xF, 0xF, true);
  x += __int_as_float(v);
  return x;
}
// hardware transpose read: quarter-wave reads 128B region, lane gets column (l&15)
template<int IMM>
static __device__ __forceinline__ u4h tr_read(unsigned va){
  u4h d;
  asm volatile("ds_read_b64_tr_b16 %0, %1 offset:%c2" : "=v"(d) : "v"(va), "i"(IMM));
  return d;
}
static __device__ __forceinline__ h8v cat8h(u4h a, u4h b){
  union { u4h p[2]; h8v v; } u; u.p[0]=a; u.p[1]=b; return u.v;
}
// A-frag (state) for plane P (0=hi,1=lo), k-slice K4 within current ping buffer
#define LDA(P,K4) cat8h(tr_read<(P)*4096+(K4)*1024>(va), tr_read<(P)*4096+(K4)*1024+128>(va))

// ---------------- workspace layout (floats) ----------------
static const size_t OFF_SENC = 0;                              // B*T*E
static const size_t OFF_QENC = OFF_SENC + (size_t)BB*TT*EE;    // B*E
static const size_t OFF_CKF  = OFF_QENC + (size_t)BB*EE;       // K*E
static const size_t OFF_XW   = OFF_CKF  + (size_t)KK*EE;       // B*T*E
static const size_t OFF_Z    = OFF_XW   + (size_t)BB*TT*EE;    // B*E
static const size_t OFF_XK   = OFF_Z    + (size_t)BB*EE;       // B*T*XK_STR
static const size_t OFF_ST   = OFF_XK   + (size_t)BB*TT*XK_STR; // B*K*E
static const size_t OFF_RH   = OFF_ST   + (size_t)BB*KK*EE;    // VOCAB*E fp16 (= V*E/2 floats)

// ---------------- kernel 0: convert R to fp16 ----------------
__global__ __launch_bounds__(256) void k_cvtR(
    const float* __restrict__ R, unsigned short* __restrict__ Rh)
{
  size_t i = ((size_t)blockIdx.x*256 + threadIdx.x)*8;
  if (i >= (size_t)VOCAB*EE) return;
  float tmp[8];
  *(float4*)&tmp[0] = *(const float4*)(R+i);
  *(float4*)&tmp[4] = *(const float4*)(R+i+4);
  h8v h;
  #pragma unroll
  for (int j=0;j<8;++j) h[j] = (_Float16)tmp[j];
  *(h8v*)(Rh+i) = h;
}

// ---------------- kernel 1: embedding bag-sum (ntok fixed at 16, unrolled) ----------------
__global__ __launch_bounds__(256) void k_embed_sum(
    const int* __restrict__ tok, const float* __restrict__ emb,
    const float* __restrict__ mask, float* __restrict__ out,
    int nrow)
{
  int tid = threadIdx.x;
  int row = blockIdx.x*8 + (tid>>5);
  if (row >= nrow) return;
  int e4 = (tid&31)*4;
  float4 acc = make_float4(0.f,0.f,0.f,0.f);
  #pragma unroll
  for (int s=0; s<16; ++s) {
    int id = tok[row*16 + s];
    float4 ev = *(const float4*)(emb + (size_t)id*EE + e4);
    float4 mv = *(const float4*)(mask + s*EE + e4);
    acc.x += ev.x*mv.x; acc.y += ev.y*mv.y; acc.z += ev.z*mv.z; acc.w += ev.w*mv.w;
  }
  *(float4*)(out + (size_t)row*EE + e4) = acc;
}

// ---------------- kernel 2: Ckf[k][f] = bias[f] + keys[k] . V[f] ----------------
__global__ __launch_bounds__(128) void k_ckf(
    const float* __restrict__ emb, const float* __restrict__ V,
    const float* __restrict__ bias, float* __restrict__ Ckf)
{
  int k = blockIdx.x;
  int f = threadIdx.x;
  const float* key = emb + (size_t)(VOCAB-KK+k)*EE;
  const float* vr  = V + (size_t)f*EE;
  float acc = bias[f];
  for (int e=0; e<EE; e+=4) {
    float4 kv = *(const float4*)(key + e);
    float4 vv = *(const float4*)(vr + e);
    acc += kv.x*vv.x + kv.y*vv.y + kv.z*vv.z + kv.w*vv.w;
  }
  Ckf[k*EE + f] = acc;
}

// ---------------- kernel 3: xw = senc@W^T  and  xk = senc@keys^T (padded) --------
__global__ __launch_bounds__(256) void k_xw(
    const float* __restrict__ senc, const float* __restrict__ W,
    const float* __restrict__ emb, float* __restrict__ xw,
    float* __restrict__ xk)
{
  __shared__ float xs[64*EE];
  __shared__ float keys_s[KK*EE];
  int tid = threadIdx.x;
  int r0 = blockIdx.x*64;
  for (int i=0;i<8;++i){
    int idx = tid + i*256; int r = idx>>5; int c4 = (idx&31)*4;
    *(float4*)(xs + r*EE + c4) = *(const float4*)(senc + (size_t)(r0+r)*EE + c4);
  }
  for (int idx=tid; idx<KK*EE; idx+=256)
    keys_s[idx] = emb[(size_t)(VOCAB-KK + (idx>>7))*EE + (idx&127)];
  __syncthreads();
  int f  = tid & 127;
  int rh = tid >> 7;
  float acc[32];
  #pragma unroll
  for (int i=0;i<32;++i) acc[i]=0.f;
  const float* wr = W + (size_t)f*EE;
  for (int e4=0; e4<EE; e4+=4) {
    float4 w4 = *(const float4*)(wr + e4);
    #pragma unroll
    for (int rr=0; rr<32; ++rr) {
      float4 x4 = *(const float4*)(xs + (rh*32+rr)*EE + e4);
      acc[rr] += w4.x*x4.x + w4.y*x4.y + w4.z*x4.z + w4.w*x4.w;
    }
  }
  #pragma unroll
  for (int rr=0; rr<32; ++rr)
    xw[(size_t)(r0 + rh*32 + rr)*EE + f] = acc[rr];
  for (int i=0;i<5;++i){
    int task = tid + i*256;
    int r = task/KK, k = task - r*KK;
    float a = 0.f;
    for (int e=0; e<EE; e+=4){
      float4 x4 = *(const float4*)(xs + r*EE + e);
      float4 k4 = *(const float4*)(keys_s + k*EE + e);
      a += x4.x*k4.x + x4.y*k4.y + x4.z*k4.z + x4.w*k4.w;
    }
    int ki = k < 10 ? k : k + 2;   // halves at 0 and 12
    xk[(size_t)(r0+r)*XK_STR + ki] = a;
  }
}

// ---------------- kernel 4: MFMA scan — frozen R13 structure (validated 242 us) ----
struct ScanLds {
  unsigned short st[2][2][EE][16];  // 16384 B (buf, plane hi/lo, e, k-row)
  unsigned short xp[2][2][EE];      // 1024 B
  float npart[2][4][16];            // 512 B
};

__global__ __launch_bounds__(256) void k_scan(
    const float* __restrict__ emb, const float* __restrict__ U,
    const float* __restrict__ senc, const float* __restrict__ xw,
    const float* __restrict__ xk, const float* __restrict__ Ckf,
    const float* __restrict__ prelu_a, float* __restrict__ zst)
{
  __shared__ ScanLds L;
  int tid = threadIdx.x;
  int bid = blockIdx.x;
  int b   = bid >> 1, kb = bid & 1;
  int l   = tid & 63, cg = tid >> 6;
  int q   = l >> 4,  c  = l & 15;
  int col[2] = { cg*32 + c, cg*32 + 16 + c };

  for (int idx = tid; idx < 2*2*EE*16; idx += 256) ((unsigned short*)L.st)[idx] = 0;
  __syncthreads();
  for (int idx = tid; idx < KB_ROWS*EE; idx += 256){
    int row = idx >> 7, e = idx & 127;
    float v = emb[(size_t)(VOCAB - KK + kb*KB_ROWS + row)*EE + e];
    _Float16 hb = (_Float16)v;
    _Float16 lb = (_Float16)(v - (float)hb);
    L.st[0][0][e][row] = h1u(hb);
    L.st[0][1][e][row] = h1u(lb);
  }
  h8v bh[2][4], bl[2][4];
  #pragma unroll
  for (int nt=0;nt<2;++nt)
    #pragma unroll
    for (int kk=0;kk<4;++kk){
      float tmp[8];
      const float* up = U + (size_t)col[nt]*EE + kk*32 + q*8;
      *(float4*)&tmp[0] = *(const float4*)up;
      *(float4*)&tmp[4] = *(const float4*)(up+4);
      split2_8(tmp, bh[nt][kk], bl[nt][kk]);
    }
  float Creg[2][4], pa2[2], nsv[2][4];
  bool realr[4];
  #pragma unroll
  for (int r=0;r<4;++r) realr[r] = (4*q + r) < KB_ROWS;
  #pragma unroll
  for (int nt=0;nt<2;++nt){
    pa2[nt] = prelu_a[col[nt]];
    #pragma unroll
    for (int r=0;r<4;++r){
      int lr = 4*q + r;
      Creg[nt][r] = realr[r] ? Ckf[(kb*KB_ROWS+lr)*EE + col[nt]] : 0.f;
      nsv[nt][r]  = realr[r] ? emb[(size_t)(VOCAB-KK+kb*KB_ROWS+lr)*EE + col[nt]] : 0.f;
    }
  }

  const float* xrow  = senc + (size_t)b*TT*EE;
  const float* xwrow = xw   + (size_t)b*TT*EE;
  const float* xkrow = xk   + (size_t)b*TT*XK_STR + kb*12;

  if (tid < EE){
    float v = xrow[tid];
    _Float16 hb = (_Float16)v;
    _Float16 lb = (_Float16)(v - (float)hb);
    L.xp[0][0][tid] = h1u(hb); L.xp[0][1][tid] = h1u(lb);
  }
  float xwc[2] = { xwrow[col[0]], xwrow[col[1]] };
  float xkc[4];
  {
    f4v xk4 = {0.f,0.f,0.f,0.f};
    if (q < 3) xk4 = *(const f4v*)(xkrow + 4*q);
    #pragma unroll
    for (int r=0;r<4;++r) xkc[r] = realr[r] ? xk4[r] : 0.f;
  }

  unsigned va0 = (unsigned)(uintptr_t)&L.st[0][0][0][0] + q*256 + c*8;
  __syncthreads();

  for (int t=0; t<TT; ++t){
    int p = t & 1, pn = p ^ 1;
    unsigned va = va0 + p*8192;
    const unsigned short (*xpp)[EE] = L.xp[p];

    float invr[4];
    if (t > 0){
      f4v p0 = *(const f4v*)&L.npart[p][0][4*q];
      f4v p1 = *(const f4v*)&L.npart[p][1][4*q];
      f4v p2 = *(const f4v*)&L.npart[p][2][4*q];
      f4v p3 = *(const f4v*)&L.npart[p][3][4*q];
      f4v ss = p0 + p1 + p2 + p3;
      #pragma unroll
      for (int r=0;r<4;++r)
        invr[r] = __builtin_amdgcn_rcpf(__builtin_amdgcn_sqrtf(ss[r]) + 1e-8f);
    } else {
      #pragma unroll
      for (int r=0;r<4;++r) invr[r] = 1.0f;
    }

    float nxv = 0.f, xwn[2] = {0.f,0.f};
    f4v xk4n = {0.f,0.f,0.f,0.f};
    if (t+1 < TT){
      if (tid < EE) nxv = xrow[(size_t)(t+1)*EE + tid];
      xwn[0] = xwrow[(size_t)(t+1)*EE + col[0]];
      xwn[1] = xwrow[(size_t)(t+1)*EE + col[1]];
      if (q < 3) xk4n = *(const f4v*)(xkrow + (size_t)(t+1)*XK_STR + 4*q);
    }

    h8v Ah[4] = { LDA(0,0), LDA(0,1), LDA(0,2), LDA(0,3) };
    h8v Al[4] = { LDA(1,0), LDA(1,1), LDA(1,2), LDA(1,3) };
    asm volatile("s_waitcnt lgkmcnt(0)" ::: "memory");
    __builtin_amdgcn_sched_barrier(0);

    f4v z4 = {0.f,0.f,0.f,0.f};
    f4v acc[2][2] = {{z4,z4},{z4,z4}};
    f4v gac[2] = {z4,z4};
    #pragma unroll
    for (int kk=0; kk<4; ++kk){
      int h = kk>>1;
      h8v xh = *(const h8v*)&xpp[0][kk*32 + q*8];
      h8v xl = *(const h8v*)&xpp[1][kk*32 + q*8];
      #pragma unroll
      for (int nt=0;nt<2;++nt){
        acc[nt][h] = MFMA16(Al[kk], bh[nt][kk], acc[nt][h]);
        acc[nt][h] = MFMA16(Ah[kk], bl[nt][kk], acc[nt][h]);
        acc[nt][h] = MFMA16(Ah[kk], bh[nt][kk], acc[nt][h]);
      }
      gac[h] = MFMA16(Al[kk], xh, gac[h]);
      gac[h] = MFMA16(Ah[kk], xl, gac[h]);
      gac[h] = MFMA16(Ah[kk], xh, gac[h]);
    }
    f4v acc0 = acc[0][0] + acc[0][1];
    f4v acc1 = acc[1][0] + acc[1][1];
    f4v gacc = gac[0] + gac[1];

    float s2[4];
    #pragma unroll
    for (int r=0;r<4;++r){
      float graw = gacc[r]*invr[r] + xkc[r];
      float g = __builtin_amdgcn_rcpf(1.0f + __builtin_amdgcn_exp2f(-1.442695040889f * graw));
      float s2r = 0.f;
      #pragma unroll
      for (int nt=0;nt<2;++nt){
        float so = nsv[nt][r] * invr[r];
        float cv = (nt ? acc1[r] : acc0[r])*invr[r] + Creg[nt][r] + xwc[nt];
        cv = cv > 0.f ? cv : pa2[nt]*cv;
        float n = so + g*cv;
        nsv[nt][r] = realr[r] ? (n > 0.f ? n : 1.0f) : 0.f;
        s2r += n*n;
      }
      s2[r] = dpp_add16(s2r);
    }
    if (c == 0){
      f4v np; np[0]=s2[0]; np[1]=s2[1]; np[2]=s2[2]; np[3]=s2[3];
      *(f4v*)&L.npart[pn][cg][4*q] = np;
    }

    #pragma unroll
    for (int nt=0;nt<2;++nt){
      float v0=nsv[nt][0], v1=nsv[nt][1], v2=nsv[nt][2], v3=nsv[nt][3];
      fp2v pa = __builtin_amdgcn_cvt_pkrtz(v0, v1);
      fp2v pb = __builtin_amdgcn_cvt_pkrtz(v2, v3);
      float r0 = v0 - pk_lo(pa);
      float r1 = v1 - pk_hi(pa);
      float r2 = v2 - pk_lo(pb);
      float r3 = v3 - pk_hi(pb);
      fp2v pc = __builtin_amdgcn_cvt_pkrtz(r0, r1);
      fp2v pd = __builtin_amdgcn_cvt_pkrtz(r2, r3);
      *(uint2*)&L.st[pn][0][col[nt]][4*q] = make_uint2(pk2u(pa), pk2u(pb));
      *(uint2*)&L.st[pn][1][col[nt]][4*q] = make_uint2(pk2u(pc), pk2u(pd));
    }
    if (t+1 < TT && tid < EE){
      _Float16 hb = (_Float16)nxv;
      _Float16 lb = (_Float16)(nxv - (float)hb);
      L.xp[pn][0][tid] = h1u(hb); L.xp[pn][1][tid] = h1u(lb);
    }
    xwc[0]=xwn[0]; xwc[1]=xwn[1];
    #pragma unroll
    for (int r=0;r<4;++r) xkc[r] = realr[r] ? xk4n[r] : 0.f;
    __syncthreads();
  }

  {
    int pf = TT & 1;
    f4v p0 = *(const f4v*)&L.npart[pf][0][4*q];
    f4v p1 = *(const f4v*)&L.npart[pf][1][4*q];
    f4v p2 = *(const f4v*)&L.npart[pf][2][4*q];
    f4v p3 = *(const f4v*)&L.npart[pf][3][4*q];
    f4v ss = p0 + p1 + p2 + p3;
    #pragma unroll
    for (int r=0;r<4;++r){
      if (realr[r]){
        float inv = __builtin_amdgcn_rcpf(__builtin_amdgcn_sqrtf(ss[r]) + 1e-8f);
        #pragma unroll
        for (int nt=0;nt<2;++nt)
          zst[((size_t)b*KK + kb*KB_ROWS + 4*q + r)*EE + col[nt]] = nsv[nt][r]*inv;
      }
    }
  }
}

// ---------------- kernel 4b: tail (attention + u + z) ----------------
__global__ __launch_bounds__(128) void k_tail(
    const float* __restrict__ zst, const float* __restrict__ qenc,
    const float* __restrict__ prelu_a, const float* __restrict__ H,
    float* __restrict__ zout)
{
  __shared__ float st[KK*EE];
  __shared__ float us[EE];
  __shared__ float red[2][KK];
  __shared__ float gs[KK];
  int b = blockIdx.x, tid = threadIdx.x;
  for (int i = tid; i < KK*EE; i += 128) st[i] = zst[(size_t)b*KK*EE + i];
  float qv = qenc[(size_t)b*EE + tid];
  __syncthreads();
  int wv = tid >> 6, ln = tid & 63;
  for (int k=0;k<KK;++k){
    float p = qv * st[k*EE + tid];
    #pragma unroll
    for (int off=32; off; off>>=1) p += __shfl_xor(p, off);
    if (ln == 0) red[wv][k] = p;
  }
  __syncthreads();
  if (tid == 0){
    float mx = -1e30f, gg[KK];
    for (int k=0;k<KK;++k){ float v = red[0][k]+red[1][k]; gg[k]=v; mx = fmaxf(mx, v); }
    float s = 0.f;
    for (int k=0;k<KK;++k){ float e_ = expf(gg[k]-mx); gg[k]=e_; s += e_; }
    for (int k=0;k<KK;++k) gs[k] = gg[k]/s;
  }
  __syncthreads();
  float u_ = 0.f;
  #pragma unroll
  for (int k=0;k<KK;++k) u_ += gs[k]*st[k*EE + tid];
  us[tid] = u_;
  __syncthreads();
  float hp = 0.f;
  const float* hr = H + (size_t)tid*EE;
  for (int e=0; e<EE; e+=4){
    float4 h4 = *(const float4*)(hr + e);
    float4 u4 = *(const float4*)(us + e);
    hp += h4.x*u4.x + h4.y*u4.y + h4.z*u4.z + h4.w*u4.w;
  }
  float zv = qv + hp;
  float pat = prelu_a[tid];
  zv = zv > 0.f ? zv : pat*zv;
  zout[(size_t)b*EE + tid] = zv;
}

// ---------------- kernel 5: y = z @ Rh^T, fp16 R (single-term), z 2-term ----------
// 2 M-tiles/block (R13 shape); R traffic halved via fp16.
__global__ __launch_bounds__(256) void k_out(
    const float* __restrict__ z, const unsigned short* __restrict__ Rh,
    float* __restrict__ y)
{
  int tid = threadIdx.x;
  int w = tid >> 6, l = tid & 63;
  int q = l >> 4, cc = l & 15;
  int b0 = blockIdx.y * 32;
  int vbase = blockIdx.x * 256 + w * 64;

  h8v ah[2][4], al[2][4];
  #pragma unroll
  for (int mt=0;mt<2;++mt){
    const float* zr = z + (size_t)(b0 + mt*16 + cc)*EE;
    #pragma unroll
    for (int kk=0;kk<4;++kk){
      float tmp[8];
      *(float4*)&tmp[0] = *(const float4*)(zr + kk*32 + q*8);
      *(float4*)&tmp[4] = *(const float4*)(zr + kk*32 + q*8 + 4);
      split2_8(tmp, ah[mt][kk], al[mt][kk]);
    }
  }
  #pragma unroll
  for (int vt=0; vt<4; ++vt){
    int v = vbase + vt*16 + cc;
    int vc = v < VOCAB ? v : VOCAB-1;
    const unsigned short* rr = Rh + (size_t)vc*EE;
    h8v bh[4];
    #pragma unroll
    for (int kk=0;kk<4;++kk)
      bh[kk] = *(const h8v*)(rr + kk*32 + q*8);
    f4v acc0 = {0.f,0.f,0.f,0.f};
    f4v acc1 = {0.f,0.f,0.f,0.f};
    #pragma unroll
    for (int kk=0;kk<4;++kk){
      acc0 = MFMA16(al[0][kk], bh[kk], acc0);
      acc0 = MFMA16(ah[0][kk], bh[kk], acc0);
      acc1 = MFMA16(al[1][kk], bh[kk], acc1);
      acc1 = MFMA16(ah[1][kk], bh[kk], acc1);
    }
    if (v < VOCAB){
      #pragma unroll
      for (int r=0;r<4;++r){
        y[(size_t)(b0 + q*4 + r)*VOCAB + v]      = acc0[r];
        y[(size_t)(b0 + 16 + q*4 + r)*VOCAB + v] = acc1[r];
      }
    }
  }
}

// ---------------- launch ----------------
extern "C" void kernel_launch(void* const* d_in, const int* in_sizes, int n_in,
                              void* d_out, int out_size, void* d_ws, size_t ws_size,
                              hipStream_t stream)
{
  const int*   story = (const int*)d_in[0];
  const int*   query = (const int*)d_in[1];
  const float* emb   = (const float*)d_in[2];
  const float* smask = (const float*)d_in[3];
  const float* qmask = (const float*)d_in[4];
  const float* pa    = (const float*)d_in[5];
  const float* U     = (const float*)d_in[6];
  const float* V     = (const float*)d_in[7];
  const float* W     = (const float*)d_in[8];
  const float* bias  = (const float*)d_in[9];
  const float* H     = (const float*)d_in[10];
  const float* R     = (const float*)d_in[11];
  float* y  = (float*)d_out;
  float* ws = (float*)d_ws;

  float* s_enc = ws + OFF_SENC;
  float* q_enc = ws + OFF_QENC;
  float* Ckf   = ws + OFF_CKF;
  float* xw    = ws + OFF_XW;
  float* z     = ws + OFF_Z;
  float* xk    = ws + OFF_XK;
  float* zst   = ws + OFF_ST;
  unsigned short* Rh = (unsigned short*)(ws + OFF_RH);

  k_cvtR<<<dim3((VOCAB*EE/8 + 255)/256), 256, 0, stream>>>(R, Rh);
  k_embed_sum<<<dim3(BB*TT/8), 256, 0, stream>>>(story, emb, smask, s_enc, BB*TT);
  k_embed_sum<<<dim3(BB/8),    256, 0, stream>>>(query, emb, qmask, q_enc, BB);
  k_ckf<<<dim3(KK), 128, 0, stream>>>(emb, V, bias, Ckf);
  k_xw<<<dim3(BB*TT/64), 256, 0, stream>>>(s_enc, W, emb, xw, xk);

  k_scan<<<dim3(BB*2), 256, 0, stream>>>(emb, U, s_enc, xw, xk, Ckf, pa, zst);
  k_tail<<<dim3(BB), 128, 0, stream>>>(zst, q_enc, pa, H, z);

  k_out<<<dim3((VOCAB+255)/256, BB/32), 256, 0, stream>>>(z, Rh, y);
}

// Round 16
// 363.444 us; speedup vs baseline: 1.0753x; 1.0251x over previous
//
#include <hip/hip_runtime.h>
#include <hip/hip_bf16.h>
#include <stdint.h>

#define BB 256
#define TT 128
#define SS 16
#define QQ 16
#define EE 128
#define KK 20
#define VOCAB 50020
#define KB_ROWS 10   // k-rows per scan block (2 blocks per batch)
#define XK_STR 24    // padded xk row stride (halves at 0 and 12, 16B-aligned)

#define NCVT  3127   // ceil(VOCAB*EE/8/256)
#define NSTORY (BB*TT/8)
#define NQUERY (BB/8)

typedef __attribute__((ext_vector_type(8))) _Float16 h8v;         // 8 fp16 (4 VGPR)
typedef __attribute__((ext_vector_type(2))) __fp16 fp2v;          // builtin's return type
typedef __attribute__((ext_vector_type(4))) unsigned short u4h;   // 4 x u16 (b64)
typedef __attribute__((ext_vector_type(4))) float f4v;            // MFMA acc
#define MFMA16(a,b,c) __builtin_amdgcn_mfma_f32_16x16x32_f16(a,b,c,0,0,0)

static __device__ __forceinline__ unsigned pk2u(fp2v h){
  union { fp2v h; unsigned u; } c; c.h = h; return c.u;
}
static __device__ __forceinline__ float pk_lo(fp2v h){ return (float)h[0]; }
static __device__ __forceinline__ float pk_hi(fp2v h){ return (float)h[1]; }
static __device__ __forceinline__ unsigned short h1u(_Float16 h){
  union { _Float16 h; unsigned short u; } c; c.h = h; return c.u;
}
// fp16 2-term split of 8 f32 (RN, used outside the hot loop)
static __device__ __forceinline__ void split2_8(const float* v, h8v& h, h8v& l){
  #pragma unroll
  for (int j=0;j<8;++j){
    _Float16 hb = (_Float16)v[j];
    float hf = (float)hb;
    h[j] = hb;
    l[j] = (_Float16)(v[j]-hf);
  }
}
// 16-lane row sum via DPP (quad_perm xor1, xor2, row_ror:4, row_ror:8)
static __device__ __forceinline__ float dpp_add16(float x){
  int v;
  v = __builtin_amdgcn_update_dpp(0, __float_as_int(x), 0xB1, 0xF, 0xF, true);
  x += __int_as_float(v);
  v = __builtin_amdgcn_update_dpp(0, __float_as_int(x), 0x4E, 0xF, 0xF, true);
  x += __int_as_float(v);
  v = __builtin_amdgcn_update_dpp(0, __float_as_int(x), 0x124, 0xF, 0xF, true);
  x += __int_as_float(v);
  v = __builtin_amdgcn_update_dpp(0, __float_as_int(x), 0x128, 0xF, 0xF, true);
  x += __int_as_float(v);
  return x;
}
// hardware transpose read: quarter-wave reads 128B region, lane gets column (l&15)
template<int IMM>
static __device__ __forceinline__ u4h tr_read(unsigned va){
  u4h d;
  asm volatile("ds_read_b64_tr_b16 %0, %1 offset:%c2" : "=v"(d) : "v"(va), "i"(IMM));
  return d;
}
static __device__ __forceinline__ h8v cat8h(u4h a, u4h b){
  union { u4h p[2]; h8v v; } u; u.p[0]=a; u.p[1]=b; return u.v;
}
// A-frag (state) for plane P (0=hi,1=lo), k-slice K4 within current ping buffer
#define LDA(P,K4) cat8h(tr_read<(P)*4096+(K4)*1024>(va), tr_read<(P)*4096+(K4)*1024+128>(va))

// ---------------- workspace layout (floats) ----------------
static const size_t OFF_SENC = 0;                              // B*T*E
static const size_t OFF_QENC = OFF_SENC + (size_t)BB*TT*EE;    // B*E
static const size_t OFF_CKF  = OFF_QENC + (size_t)BB*EE;       // K*E
static const size_t OFF_XW   = OFF_CKF  + (size_t)KK*EE;       // B*T*E
static const size_t OFF_Z    = OFF_XW   + (size_t)BB*TT*EE;    // B*E
static const size_t OFF_XK   = OFF_Z    + (size_t)BB*EE;       // B*T*XK_STR
static const size_t OFF_ST   = OFF_XK   + (size_t)BB*TT*XK_STR; // B*K*E
static const size_t OFF_RH   = OFF_ST   + (size_t)BB*KK*EE;    // VOCAB*E fp16 (= V*E/2 floats)

// ---------------- kernel 1: grid-partitioned prologue ----------------
// blocks [0,NCVT): R->fp16 | [NCVT,+NSTORY): story embed | +NQUERY: query embed | +KK: ckf
__global__ __launch_bounds__(256) void k_pro(
    const int* __restrict__ story, const int* __restrict__ query,
    const float* __restrict__ emb, const float* __restrict__ smask,
    const float* __restrict__ qmask, const float* __restrict__ V,
    const float* __restrict__ bias, const float* __restrict__ R,
    float* __restrict__ senc, float* __restrict__ qenc,
    float* __restrict__ Ckf, unsigned short* __restrict__ Rh)
{
  int bid = blockIdx.x;
  int tid = threadIdx.x;
  if (bid < NCVT){
    size_t i = ((size_t)bid*256 + tid)*8;
    if (i >= (size_t)VOCAB*EE) return;
    float tmp[8];
    *(float4*)&tmp[0] = *(const float4*)(R+i);
    *(float4*)&tmp[4] = *(const float4*)(R+i+4);
    h8v h;
    #pragma unroll
    for (int j=0;j<8;++j) h[j] = (_Float16)tmp[j];
    *(h8v*)(Rh+i) = h;
  } else if (bid < NCVT + NSTORY){
    int row = (bid - NCVT)*8 + (tid>>5);
    int e4 = (tid&31)*4;
    float4 acc = make_float4(0.f,0.f,0.f,0.f);
    #pragma unroll
    for (int s=0; s<SS; ++s) {
      int id = story[(size_t)row*SS + s];
      float4 ev = *(const float4*)(emb + (size_t)id*EE + e4);
      float4 mv = *(const float4*)(smask + s*EE + e4);
      acc.x += ev.x*mv.x; acc.y += ev.y*mv.y; acc.z += ev.z*mv.z; acc.w += ev.w*mv.w;
    }
    *(float4*)(senc + (size_t)row*EE + e4) = acc;
  } else if (bid < NCVT + NSTORY + NQUERY){
    int row = (bid - NCVT - NSTORY)*8 + (tid>>5);
    int e4 = (tid&31)*4;
    float4 acc = make_float4(0.f,0.f,0.f,0.f);
    #pragma unroll
    for (int s=0; s<QQ; ++s) {
      int id = query[(size_t)row*QQ + s];
      float4 ev = *(const float4*)(emb + (size_t)id*EE + e4);
      float4 mv = *(const float4*)(qmask + s*EE + e4);
      acc.x += ev.x*mv.x; acc.y += ev.y*mv.y; acc.z += ev.z*mv.z; acc.w += ev.w*mv.w;
    }
    *(float4*)(qenc + (size_t)row*EE + e4) = acc;
  } else {
    int k = bid - NCVT - NSTORY - NQUERY;
    if (tid < 128){
      int f = tid;
      const float* key = emb + (size_t)(VOCAB-KK+k)*EE;
      const float* vr  = V + (size_t)f*EE;
      float acc = bias[f];
      for (int e=0; e<EE; e+=4) {
        float4 kv = *(const float4*)(key + e);
        float4 vv = *(const float4*)(vr + e);
        acc += kv.x*vv.x + kv.y*vv.y + kv.z*vv.z + kv.w*vv.w;
      }
      Ckf[k*EE + f] = acc;
    }
  }
}

// ---------------- kernel 3: xw = senc@W^T  and  xk = senc@keys^T (padded) --------
__global__ __launch_bounds__(256) void k_xw(
    const float* __restrict__ senc, const float* __restrict__ W,
    const float* __restrict__ emb, float* __restrict__ xw,
    float* __restrict__ xk)
{
  __shared__ float xs[64*EE];
  __shared__ float keys_s[KK*EE];
  int tid = threadIdx.x;
  int r0 = blockIdx.x*64;
  for (int i=0;i<8;++i){
    int idx = tid + i*256; int r = idx>>5; int c4 = (idx&31)*4;
    *(float4*)(xs + r*EE + c4) = *(const float4*)(senc + (size_t)(r0+r)*EE + c4);
  }
  for (int idx=tid; idx<KK*EE; idx+=256)
    keys_s[idx] = emb[(size_t)(VOCAB-KK + (idx>>7))*EE + (idx&127)];
  __syncthreads();
  int f  = tid & 127;
  int rh = tid >> 7;
  float acc[32];
  #pragma unroll
  for (int i=0;i<32;++i) acc[i]=0.f;
  const float* wr = W + (size_t)f*EE;
  for (int e4=0; e4<EE; e4+=4) {
    float4 w4 = *(const float4*)(wr + e4);
    #pragma unroll
    for (int rr=0; rr<32; ++rr) {
      float4 x4 = *(const float4*)(xs + (rh*32+rr)*EE + e4);
      acc[rr] += w4.x*x4.x + w4.y*x4.y + w4.z*x4.z + w4.w*x4.w;
    }
  }
  #pragma unroll
  for (int rr=0; rr<32; ++rr)
    xw[(size_t)(r0 + rh*32 + rr)*EE + f] = acc[rr];
  for (int i=0;i<5;++i){
    int task = tid + i*256;
    int r = task/KK, k = task - r*KK;
    float a = 0.f;
    for (int e=0; e<EE; e+=4){
      float4 x4 = *(const float4*)(xs + r*EE + e);
      float4 k4 = *(const float4*)(keys_s + k*EE + e);
      a += x4.x*k4.x + x4.y*k4.y + x4.z*k4.z + x4.w*k4.w;
    }
    int ki = k < 10 ? k : k + 2;   // halves at 0 and 12
    xk[(size_t)(r0+r)*XK_STR + ki] = a;
  }
}

// ---------------- kernel 4: MFMA scan — frozen R13 structure (validated 242 us) ----
struct ScanLds {
  unsigned short st[2][2][EE][16];  // 16384 B (buf, plane hi/lo, e, k-row)
  unsigned short xp[2][2][EE];      // 1024 B
  float npart[2][4][16];            // 512 B
};

__global__ __launch_bounds__(256) void k_scan(
    const float* __restrict__ emb, const float* __restrict__ U,
    const float* __restrict__ senc, const float* __restrict__ xw,
    const float* __restrict__ xk, const float* __restrict__ Ckf,
    const float* __restrict__ prelu_a, float* __restrict__ zst)
{
  __shared__ ScanLds L;
  int tid = threadIdx.x;
  int bid = blockIdx.x;
  int b   = bid >> 1, kb = bid & 1;
  int l   = tid & 63, cg = tid >> 6;
  int q   = l >> 4,  c  = l & 15;
  int col[2] = { cg*32 + c, cg*32 + 16 + c };

  for (int idx = tid; idx < 2*2*EE*16; idx += 256) ((unsigned short*)L.st)[idx] = 0;
  __syncthreads();
  for (int idx = tid; idx < KB_ROWS*EE; idx += 256){
    int row = idx >> 7, e = idx & 127;
    float v = emb[(size_t)(VOCAB - KK + kb*KB_ROWS + row)*EE + e];
    _Float16 hb = (_Float16)v;
    _Float16 lb = (_Float16)(v - (float)hb);
    L.st[0][0][e][row] = h1u(hb);
    L.st[0][1][e][row] = h1u(lb);
  }
  h8v bh[2][4], bl[2][4];
  #pragma unroll
  for (int nt=0;nt<2;++nt)
    #pragma unroll
    for (int kk=0;kk<4;++kk){
      float tmp[8];
      const float* up = U + (size_t)col[nt]*EE + kk*32 + q*8;
      *(float4*)&tmp[0] = *(const float4*)up;
      *(float4*)&tmp[4] = *(const float4*)(up+4);
      split2_8(tmp, bh[nt][kk], bl[nt][kk]);
    }
  float Creg[2][4], pa2[2], nsv[2][4];
  bool realr[4];
  #pragma unroll
  for (int r=0;r<4;++r) realr[r] = (4*q + r) < KB_ROWS;
  #pragma unroll
  for (int nt=0;nt<2;++nt){
    pa2[nt] = prelu_a[col[nt]];
    #pragma unroll
    for (int r=0;r<4;++r){
      int lr = 4*q + r;
      Creg[nt][r] = realr[r] ? Ckf[(kb*KB_ROWS+lr)*EE + col[nt]] : 0.f;
      nsv[nt][r]  = realr[r] ? emb[(size_t)(VOCAB-KK+kb*KB_ROWS+lr)*EE + col[nt]] : 0.f;
    }
  }

  const float* xrow  = senc + (size_t)b*TT*EE;
  const float* xwrow = xw   + (size_t)b*TT*EE;
  const float* xkrow = xk   + (size_t)b*TT*XK_STR + kb*12;

  if (tid < EE){
    float v = xrow[tid];
    _Float16 hb = (_Float16)v;
    _Float16 lb = (_Float16)(v - (float)hb);
    L.xp[0][0][tid] = h1u(hb); L.xp[0][1][tid] = h1u(lb);
  }
  float xwc[2] = { xwrow[col[0]], xwrow[col[1]] };
  float xkc[4];
  {
    f4v xk4 = {0.f,0.f,0.f,0.f};
    if (q < 3) xk4 = *(const f4v*)(xkrow + 4*q);
    #pragma unroll
    for (int r=0;r<4;++r) xkc[r] = realr[r] ? xk4[r] : 0.f;
  }

  unsigned va0 = (unsigned)(uintptr_t)&L.st[0][0][0][0] + q*256 + c*8;
  __syncthreads();

  for (int t=0; t<TT; ++t){
    int p = t & 1, pn = p ^ 1;
    unsigned va = va0 + p*8192;
    const unsigned short (*xpp)[EE] = L.xp[p];

    float invr[4];
    if (t > 0){
      f4v p0 = *(const f4v*)&L.npart[p][0][4*q];
      f4v p1 = *(const f4v*)&L.npart[p][1][4*q];
      f4v p2 = *(const f4v*)&L.npart[p][2][4*q];
      f4v p3 = *(const f4v*)&L.npart[p][3][4*q];
      f4v ss = p0 + p1 + p2 + p3;
      #pragma unroll
      for (int r=0;r<4;++r)
        invr[r] = __builtin_amdgcn_rcpf(__builtin_amdgcn_sqrtf(ss[r]) + 1e-8f);
    } else {
      #pragma unroll
      for (int r=0;r<4;++r) invr[r] = 1.0f;
    }

    float nxv = 0.f, xwn[2] = {0.f,0.f};
    f4v xk4n = {0.f,0.f,0.f,0.f};
    if (t+1 < TT){
      if (tid < EE) nxv = xrow[(size_t)(t+1)*EE + tid];
      xwn[0] = xwrow[(size_t)(t+1)*EE + col[0]];
      xwn[1] = xwrow[(size_t)(t+1)*EE + col[1]];
      if (q < 3) xk4n = *(const f4v*)(xkrow + (size_t)(t+1)*XK_STR + 4*q);
    }

    h8v Ah[4] = { LDA(0,0), LDA(0,1), LDA(0,2), LDA(0,3) };
    h8v Al[4] = { LDA(1,0), LDA(1,1), LDA(1,2), LDA(1,3) };
    asm volatile("s_waitcnt lgkmcnt(0)" ::: "memory");
    __builtin_amdgcn_sched_barrier(0);

    f4v z4 = {0.f,0.f,0.f,0.f};
    f4v acc[2][2] = {{z4,z4},{z4,z4}};
    f4v gac[2] = {z4,z4};
    #pragma unroll
    for (int kk=0; kk<4; ++kk){
      int h = kk>>1;
      h8v xh = *(const h8v*)&xpp[0][kk*32 + q*8];
      h8v xl = *(const h8v*)&xpp[1][kk*32 + q*8];
      #pragma unroll
      for (int nt=0;nt<2;++nt){
        acc[nt][h] = MFMA16(Al[kk], bh[nt][kk], acc[nt][h]);
        acc[nt][h] = MFMA16(Ah[kk], bl[nt][kk], acc[nt][h]);
        acc[nt][h] = MFMA16(Ah[kk], bh[nt][kk], acc[nt][h]);
      }
      gac[h] = MFMA16(Al[kk], xh, gac[h]);
      gac[h] = MFMA16(Ah[kk], xl, gac[h]);
      gac[h] = MFMA16(Ah[kk], xh, gac[h]);
    }
    f4v acc0 = acc[0][0] + acc[0][1];
    f4v acc1 = acc[1][0] + acc[1][1];
    f4v gacc = gac[0] + gac[1];

    float s2[4];
    #pragma unroll
    for (int r=0;r<4;++r){
      float graw = gacc[r]*invr[r] + xkc[r];
      float g = __builtin_amdgcn_rcpf(1.0f + __builtin_amdgcn_exp2f(-1.442695040889f * graw));
      float s2r = 0.f;
      #pragma unroll
      for (int nt=0;nt<2;++nt){
        float so = nsv[nt][r] * invr[r];
        float cv = (nt ? acc1[r] : acc0[r])*invr[r] + Creg[nt][r] + xwc[nt];
        cv = cv > 0.f ? cv : pa2[nt]*cv;
        float n = so + g*cv;
        nsv[nt][r] = realr[r] ? (n > 0.f ? n : 1.0f) : 0.f;
        s2r += n*n;
      }
      s2[r] = dpp_add16(s2r);
    }
    if (c == 0){
      f4v np; np[0]=s2[0]; np[1]=s2[1]; np[2]=s2[2]; np[3]=s2[3];
      *(f4v*)&L.npart[pn][cg][4*q] = np;
    }

    #pragma unroll
    for (int nt=0;nt<2;++nt){
      float v0=nsv[nt][0], v1=nsv[nt][1], v2=nsv[nt][2], v3=nsv[nt][3];
      fp2v pa = __builtin_amdgcn_cvt_pkrtz(v0, v1);
      fp2v pb = __builtin_amdgcn_cvt_pkrtz(v2, v3);
      float r0 = v0 - pk_lo(pa);
      float r1 = v1 - pk_hi(pa);
      float r2 = v2 - pk_lo(pb);
      float r3 = v3 - pk_hi(pb);
      fp2v pc = __builtin_amdgcn_cvt_pkrtz(r0, r1);
      fp2v pd = __builtin_amdgcn_cvt_pkrtz(r2, r3);
      *(uint2*)&L.st[pn][0][col[nt]][4*q] = make_uint2(pk2u(pa), pk2u(pb));
      *(uint2*)&L.st[pn][1][col[nt]][4*q] = make_uint2(pk2u(pc), pk2u(pd));
    }
    if (t+1 < TT && tid < EE){
      _Float16 hb = (_Float16)nxv;
      _Float16 lb = (_Float16)(nxv - (float)hb);
      L.xp[pn][0][tid] = h1u(hb); L.xp[pn][1][tid] = h1u(lb);
    }
    xwc[0]=xwn[0]; xwc[1]=xwn[1];
    #pragma unroll
    for (int r=0;r<4;++r) xkc[r] = realr[r] ? xk4n[r] : 0.f;
    __syncthreads();
  }

  {
    int pf = TT & 1;
    f4v p0 = *(const f4v*)&L.npart[pf][0][4*q];
    f4v p1 = *(const f4v*)&L.npart[pf][1][4*q];
    f4v p2 = *(const f4v*)&L.npart[pf][2][4*q];
    f4v p3 = *(const f4v*)&L.npart[pf][3][4*q];
    f4v ss = p0 + p1 + p2 + p3;
    #pragma unroll
    for (int r=0;r<4;++r){
      if (realr[r]){
        float inv = __builtin_amdgcn_rcpf(__builtin_amdgcn_sqrtf(ss[r]) + 1e-8f);
        #pragma unroll
        for (int nt=0;nt<2;++nt)
          zst[((size_t)b*KK + kb*KB_ROWS + 4*q + r)*EE + col[nt]] = nsv[nt][r]*inv;
      }
    }
  }
}

// ---------------- kernel 4b: tail (attention + u + z) ----------------
__global__ __launch_bounds__(128) void k_tail(
    const float* __restrict__ zst, const float* __restrict__ qenc,
    const float* __restrict__ prelu_a, const float* __restrict__ H,
    float* __restrict__ zout)
{
  __shared__ float st[KK*EE];
  __shared__ float us[EE];
  __shared__ float red[2][KK];
  __shared__ float gs[KK];
  int b = blockIdx.x, tid = threadIdx.x;
  for (int i = tid; i < KK*EE; i += 128) st[i] = zst[(size_t)b*KK*EE + i];
  float qv = qenc[(size_t)b*EE + tid];
  __syncthreads();
  int wv = tid >> 6, ln = tid & 63;
  for (int k=0;k<KK;++k){
    float p = qv * st[k*EE + tid];
    #pragma unroll
    for (int off=32; off; off>>=1) p += __shfl_xor(p, off);
    if (ln == 0) red[wv][k] = p;
  }
  __syncthreads();
  if (tid == 0){
    float mx = -1e30f, gg[KK];
    for (int k=0;k<KK;++k){ float v = red[0][k]+red[1][k]; gg[k]=v; mx = fmaxf(mx, v); }
    float s = 0.f;
    for (int k=0;k<KK;++k){ float e_ = expf(gg[k]-mx); gg[k]=e_; s += e_; }
    for (int k=0;k<KK;++k) gs[k] = gg[k]/s;
  }
  __syncthreads();
  float u_ = 0.f;
  #pragma unroll
  for (int k=0;k<KK;++k) u_ += gs[k]*st[k*EE + tid];
  us[tid] = u_;
  __syncthreads();
  float hp = 0.f;
  const float* hr = H + (size_t)tid*EE;
  for (int e=0; e<EE; e+=4){
    float4 h4 = *(const float4*)(hr + e);
    float4 u4 = *(const float4*)(us + e);
    hp += h4.x*u4.x + h4.y*u4.y + h4.z*u4.z + h4.w*u4.w;
  }
  float zv = qv + hp;
  float pat = prelu_a[tid];
  zv = zv > 0.f ? zv : pat*zv;
  zout[(size_t)b*EE + tid] = zv;
}

// ---------------- kernel 5: y = z @ Rh^T, fp16 R single-term, 4 M-tiles/block ----
// Wave: 64 b-rows x 64 v-cols; Rh loaded once per vt, reused across 4 M-tiles.
__global__ __launch_bounds__(256) void k_out(
    const float* __restrict__ z, const unsigned short* __restrict__ Rh,
    float* __restrict__ y)
{
  int tid = threadIdx.x;
  int w = tid >> 6, l = tid & 63;
  int q = l >> 4, cc = l & 15;
  int b0 = blockIdx.y * 64;
  int vbase = blockIdx.x * 256 + w * 64;

  h8v ah[4][4], al[4][4];
  #pragma unroll
  for (int mt=0;mt<4;++mt){
    const float* zr = z + (size_t)(b0 + mt*16 + cc)*EE;
    #pragma unroll
    for (int kk=0;kk<4;++kk){
      float tmp[8];
      *(float4*)&tmp[0] = *(const float4*)(zr + kk*32 + q*8);
      *(float4*)&tmp[4] = *(const float4*)(zr + kk*32 + q*8 + 4);
      split2_8(tmp, ah[mt][kk], al[mt][kk]);
    }
  }
  #pragma unroll
  for (int vt=0; vt<4; ++vt){
    int v = vbase + vt*16 + cc;
    int vc = v < VOCAB ? v : VOCAB-1;
    const unsigned short* rr = Rh + (size_t)vc*EE;
    h8v bh[4];
    #pragma unroll
    for (int kk=0;kk<4;++kk)
      bh[kk] = *(const h8v*)(rr + kk*32 + q*8);
    f4v acc0 = {0.f,0.f,0.f,0.f};
    f4v acc1 = {0.f,0.f,0.f,0.f};
    f4v acc2 = {0.f,0.f,0.f,0.f};
    f4v acc3 = {0.f,0.f,0.f,0.f};
    #pragma unroll
    for (int kk=0;kk<4;++kk){
      acc0 = MFMA16(al[0][kk], bh[kk], acc0);
      acc0 = MFMA16(ah[0][kk], bh[kk], acc0);
      acc1 = MFMA16(al[1][kk], bh[kk], acc1);
      acc1 = MFMA16(ah[1][kk], bh[kk], acc1);
      acc2 = MFMA16(al[2][kk], bh[kk], acc2);
      acc2 = MFMA16(ah[2][kk], bh[kk], acc2);
      acc3 = MFMA16(al[3][kk], bh[kk], acc3);
      acc3 = MFMA16(ah[3][kk], bh[kk], acc3);
    }
    if (v < VOCAB){
      #pragma unroll
      for (int r=0;r<4;++r){
        y[(size_t)(b0 +      q*4 + r)*VOCAB + v] = acc0[r];
        y[(size_t)(b0 + 16 + q*4 + r)*VOCAB + v] = acc1[r];
        y[(size_t)(b0 + 32 + q*4 + r)*VOCAB + v] = acc2[r];
        y[(size_t)(b0 + 48 + q*4 + r)*VOCAB + v] = acc3[r];
      }
    }
  }
}

// ---------------- launch ----------------
extern "C" void kernel_launch(void* const* d_in, const int* in_sizes, int n_in,
                              void* d_out, int out_size, void* d_ws, size_t ws_size,
                              hipStream_t stream)
{
  const int*   story = (const int*)d_in[0];
  const int*   query = (const int*)d_in[1];
  const float* emb   = (const float*)d_in[2];
  const float* smask = (const float*)d_in[3];
  const float* qmask = (const float*)d_in[4];
  const float* pa    = (const float*)d_in[5];
  const float* U     = (const float*)d_in[6];
  const float* V     = (const float*)d_in[7];
  const float* W     = (const float*)d_in[8];
  const float* bias  = (const float*)d_in[9];
  const float* H     = (const float*)d_in[10];
  const float* R     = (const float*)d_in[11];
  float* y  = (float*)d_out;
  float* ws = (float*)d_ws;

  float* s_enc = ws + OFF_SENC;
  float* q_enc = ws + OFF_QENC;
  float* Ckf   = ws + OFF_CKF;
  float* xw    = ws + OFF_XW;
  float* z     = ws + OFF_Z;
  float* xk    = ws + OFF_XK;
  float* zst   = ws + OFF_ST;
  unsigned short* Rh = (unsigned short*)(ws + OFF_RH);

  k_pro<<<dim3(NCVT + NSTORY + NQUERY + KK), 256, 0, stream>>>(
      story, query, emb, smask, qmask, V, bias, R, s_enc, q_enc, Ckf, Rh);
  k_xw<<<dim3(BB*TT/64), 256, 0, stream>>>(s_enc, W, emb, xw, xk);

  k_scan<<<dim3(BB*2), 256, 0, stream>>>(emb, U, s_enc, xw, xk, Ckf, pa, zst);
  k_tail<<<dim3(BB), 128, 0, stream>>>(zst, q_enc, pa, H, z);

  k_out<<<dim3((VOCAB+255)/256, BB/64), 256, 0, stream>>>(z, Rh, y);
}